// Round 4
// baseline (518.089 us; speedup 1.0000x reference)
//
#include <hip/hip_runtime.h>

typedef _Float16 half_t;
typedef _Float16 half8  __attribute__((ext_vector_type(8)));
typedef _Float16 half4v __attribute__((ext_vector_type(4)));
typedef float    f32x4  __attribute__((ext_vector_type(4)));

#define ROWB   528          // padded row stride (bytes) for 64x256 f16 tiles
#define S_A    0            // x staging (read by Phase B)
#define S_B    33792        // y staging (read by Phase A) -> O (token-major)
#define SMEM_BYTES 67584    // 66 KB -> 2 blocks/CU
#define SCALE  0.17677669529663687f

// ---- prep: weights f32->f16 (q_w pre-scaled); fused bias+mask f16 [4][8][64][64]
__global__ __launch_bounds__(256) void swin_prep(
    const float* __restrict__ q_w, const float* __restrict__ kv_w,
    const float* __restrict__ proj_w, const float* __restrict__ rpb,
    const float* __restrict__ mask,
    half_t* __restrict__ w16, half_t* __restrict__ fused)
{
    int t = blockIdx.x * 256 + threadIdx.x;
    if (t < 65536)        w16[t] = (half_t)(q_w[t] * SCALE);
    else if (t < 196608)  w16[t] = (half_t)kv_w[t - 65536];
    else if (t < 262144)  w16[t] = (half_t)proj_w[t - 196608];
    else if (t < 393216) {
        int u = t - 262144;                 // [0, 131072)
        int cls = u >> 15, rest = u & 32767;
        int h = rest >> 12, i = (rest >> 6) & 63, j = rest & 63;
        int idx = ((i >> 3) - (j >> 3) + 7) * 15 + ((i & 7) - (j & 7) + 7);
        int wsel = (cls == 0) ? 0 : (cls == 1) ? 31 : (cls == 2) ? 992 : 1023;
        fused[u] = (half_t)(rpb[idx * 8 + h] + mask[(size_t)wsel * 4096 + i * 64 + j]);
    }
}

static __device__ __forceinline__ unsigned pk2(float a, float b) {
    union { _Float16 h[2]; unsigned u; } t;
    t.h[0] = (_Float16)a; t.h[1] = (_Float16)b; return t.u;
}

// C-layout (contraction axis on g*4+r over two 16-tiles) -> A/B-frag (contraction
// axis on g*8+e), l15 axis preserved. P0/P1 = the two 16-tile packed pairs.
#define BUILD_FRAG(dst, P0, P1)                                          \
    do {                                                                 \
        union { unsigned u[4]; half8 h; } _u;                            \
        _Pragma("unroll")                                                \
        for (int p = 0; p < 4; ++p) {                                    \
            int _src = (p >> 1) ? srcB : srcA;                           \
            unsigned _rlo = (unsigned)__shfl((int)(P0)[p & 1], _src);    \
            unsigned _rhi = (unsigned)__shfl((int)(P1)[p & 1], _src);    \
            _u.u[p] = hi ? _rhi : _rlo;                                  \
        }                                                                \
        dst = _u.h;                                                      \
    } while (0)

__global__ __launch_bounds__(512, 4) void swin_main(
    const float* __restrict__ x, const float* __restrict__ y,
    const float* __restrict__ q_b, const float* __restrict__ kv_b,
    const float* __restrict__ proj_b,
    const half_t* __restrict__ w16, const half_t* __restrict__ fused,
    float* __restrict__ out)
{
    __shared__ __align__(16) char sm[SMEM_BYTES];
    const int tid  = threadIdx.x;
    const int w    = tid >> 6;       // wave = head
    const int lane = tid & 63;
    const int l15  = lane & 15;
    const int g    = lane >> 4;      // 16-lane group 0..3
    const int b    = blockIdx.x;
    const int jf0  = w * 32;
    const int srcA = ((2 * g) & 3) * 16 + l15;
    const int srcB = ((2 * g + 1) & 3) * 16 + l15;
    const int hi   = g >> 1;

    const float* xb = x + (size_t)b * 16384;
    const float* yb = y + (size_t)b * 16384;
    const half_t* wkv = w16 + 65536;

    // ---------------- P0: stage x,y as f16 (batched burst) ----------------
    {
        float4 fx[8], fy[8];
        #pragma unroll
        for (int it = 0; it < 4; ++it) {
            int c = tid + it * 512;
            int row = c >> 5, c8 = c & 31;
            fx[it*2+0] = *(const float4*)(xb + row * 256 + c8 * 8);
            fx[it*2+1] = *(const float4*)(xb + row * 256 + c8 * 8 + 4);
            fy[it*2+0] = *(const float4*)(yb + row * 256 + c8 * 8);
            fy[it*2+1] = *(const float4*)(yb + row * 256 + c8 * 8 + 4);
        }
        #pragma unroll
        for (int it = 0; it < 4; ++it) {
            int c = tid + it * 512;
            int row = c >> 5, c8 = c & 31;
            half8 hx, hy;
            #pragma unroll
            for (int e = 0; e < 4; ++e) {
                hx[e]   = (half_t)(&fx[it*2+0].x)[e];
                hx[e+4] = (half_t)(&fx[it*2+1].x)[e];
                hy[e]   = (half_t)(&fy[it*2+0].x)[e];
                hy[e+4] = (half_t)(&fy[it*2+1].x)[e];
            }
            int off = row * ROWB + c8 * 16;
            *(half8*)(sm + S_A + off) = hx;
            *(half8*)(sm + S_B + off) = hy;
        }
    }
    __syncthreads();   // bar1: staging visible

    // ---------------- Phase A: K^T, V from y (reads sB) ----------------
    // K^T = w_k @ y^T  -> (token via l15, feature via g*4+r)  [swapped mfma args]
    // V   = y @ w_v^T  -> (token via g*4+r, feature via l15)  [as R2, verified]
    f32x4 kacc[2][4], vacc[4][2];
    #pragma unroll
    for (int ft = 0; ft < 2; ++ft)
        #pragma unroll
        for (int tok = 0; tok < 4; ++tok) {
            f32x4 z = {0.f,0.f,0.f,0.f}; kacc[ft][tok] = z; vacc[tok][ft] = z;
        }
    #pragma unroll
    for (int kh = 0; kh < 2; ++kh) {
        half8 wbk[4][2], wbv[4][2];
        #pragma unroll
        for (int k2 = 0; k2 < 4; ++k2) {
            int k0 = (kh * 4 + k2) * 32 + g * 8;
            #pragma unroll
            for (int ft = 0; ft < 2; ++ft) {
                int jf = jf0 + ft * 16 + l15;
                wbk[k2][ft] = *(const half8*)(wkv + jf * 256 + k0);
                wbv[k2][ft] = *(const half8*)(wkv + (256 + jf) * 256 + k0);
            }
        }
        #pragma unroll
        for (int k2 = 0; k2 < 4; ++k2) {
            int k0 = (kh * 4 + k2) * 32 + g * 8;
            half8 a[4];
            #pragma unroll
            for (int tok = 0; tok < 4; ++tok)
                a[tok] = *(const half8*)(sm + S_B + (tok * 16 + l15) * ROWB + k0 * 2);
            #pragma unroll
            for (int ft = 0; ft < 2; ++ft)
                #pragma unroll
                for (int tok = 0; tok < 4; ++tok) {
                    kacc[ft][tok] = __builtin_amdgcn_mfma_f32_16x16x32_f16(wbk[k2][ft], a[tok], kacc[ft][tok], 0, 0, 0);
                    vacc[tok][ft] = __builtin_amdgcn_mfma_f32_16x16x32_f16(a[tok], wbv[k2][ft], vacc[tok][ft], 0, 0, 0);
                }
        }
    }
    __syncthreads();   // bar2: ALL sB reads done -> O may overwrite sB later

    // pack K^T (+bias, feature via g*4+r) and V (+bias, feature via l15)
    unsigned kp[2][4][2], vp[4][2][2];
    {
        #pragma unroll
        for (int ft = 0; ft < 2; ++ft) {
            float4 kb4 = *(const float4*)(kv_b + jf0 + ft * 16 + g * 4);
            #pragma unroll
            for (int tok = 0; tok < 4; ++tok) {
                kp[ft][tok][0] = pk2(kacc[ft][tok][0] + kb4.x, kacc[ft][tok][1] + kb4.y);
                kp[ft][tok][1] = pk2(kacc[ft][tok][2] + kb4.z, kacc[ft][tok][3] + kb4.w);
            }
        }
        #pragma unroll
        for (int ft = 0; ft < 2; ++ft) {
            float vb = kv_b[256 + jf0 + ft * 16 + l15];
            #pragma unroll
            for (int tok = 0; tok < 4; ++tok) {
                vp[tok][ft][0] = pk2(vacc[tok][ft][0] + vb, vacc[tok][ft][1] + vb);
                vp[tok][ft][1] = pk2(vacc[tok][ft][2] + vb, vacc[tok][ft][3] + vb);
            }
        }
    }

    // ---------------- Phase B: Q^T = (w_q*scale) @ x^T (reads sA) ----------------
    unsigned qp[2][4][2];
    {
        f32x4 qacc[2][4];
        #pragma unroll
        for (int ft = 0; ft < 2; ++ft)
            #pragma unroll
            for (int tok = 0; tok < 4; ++tok) { f32x4 z = {0.f,0.f,0.f,0.f}; qacc[ft][tok] = z; }
        #pragma unroll
        for (int kh = 0; kh < 2; ++kh) {
            half8 wbq[4][2];
            #pragma unroll
            for (int k2 = 0; k2 < 4; ++k2) {
                int k0 = (kh * 4 + k2) * 32 + g * 8;
                #pragma unroll
                for (int ft = 0; ft < 2; ++ft)
                    wbq[k2][ft] = *(const half8*)(w16 + (jf0 + ft * 16 + l15) * 256 + k0);
            }
            #pragma unroll
            for (int k2 = 0; k2 < 4; ++k2) {
                int k0 = (kh * 4 + k2) * 32 + g * 8;
                half8 a[4];
                #pragma unroll
                for (int tok = 0; tok < 4; ++tok)
                    a[tok] = *(const half8*)(sm + S_A + (tok * 16 + l15) * ROWB + k0 * 2);
                #pragma unroll
                for (int ft = 0; ft < 2; ++ft)
                    #pragma unroll
                    for (int tok = 0; tok < 4; ++tok)
                        qacc[ft][tok] = __builtin_amdgcn_mfma_f32_16x16x32_f16(wbq[k2][ft], a[tok], qacc[ft][tok], 0, 0, 0);
            }
        }
        #pragma unroll
        for (int ft = 0; ft < 2; ++ft) {
            float4 qb4 = *(const float4*)(q_b + jf0 + ft * 16 + g * 4);
            #pragma unroll
            for (int tok = 0; tok < 4; ++tok) {
                qp[ft][tok][0] = pk2(qacc[ft][tok][0] + qb4.x * SCALE, qacc[ft][tok][1] + qb4.y * SCALE);
                qp[ft][tok][1] = pk2(qacc[ft][tok][2] + qb4.z * SCALE, qacc[ft][tok][3] + qb4.w * SCALE);
            }
        }
    }

    // ---------------- Phase C: attention, all in registers ----------------
    {
        const int wi = b & 1023;
        const int cls = ((((wi >> 5) == 31) ? 2 : 0)) | (((wi & 31) == 31) ? 1 : 0);
        const half_t* fb = fused + ((size_t)cls * 8 + w) * 4096;

        // fused bias+mask loads (issued early; L2/L3-resident)
        half4v fm[4][4];   // [nt][mt]
        #pragma unroll
        for (int nt = 0; nt < 4; ++nt)
            #pragma unroll
            for (int mt = 0; mt < 4; ++mt)
                fm[nt][mt] = *(const half4v*)(fb + (nt * 16 + l15) * 64 + mt * 16 + g * 4);

        // build K,Q frags from packed regs (kp/qp die here)
        half8 ka[4], qf[4];
        #pragma unroll
        for (int mt = 0; mt < 4; ++mt) BUILD_FRAG(ka[mt], kp[0][mt], kp[1][mt]);
        #pragma unroll
        for (int nt = 0; nt < 4; ++nt) BUILD_FRAG(qf[nt], qp[0][nt], qp[1][nt]);

        // S^T = K @ Q^T : t[mt][nt][r] -> j = mt*16+g*4+r (kv), i = nt*16+l15 (q)
        f32x4 t[4][4];
        #pragma unroll
        for (int mt = 0; mt < 4; ++mt)
            #pragma unroll
            for (int nt = 0; nt < 4; ++nt) {
                f32x4 z = {0.f,0.f,0.f,0.f};
                t[mt][nt] = __builtin_amdgcn_mfma_f32_16x16x32_f16(ka[mt], qf[nt], z, 0, 0, 0);
            }

        // softmax over j (within-lane 16 + cross-g shfl), bias added first
        #pragma unroll
        for (int nt = 0; nt < 4; ++nt) {
            #pragma unroll
            for (int mt = 0; mt < 4; ++mt)
                #pragma unroll
                for (int r = 0; r < 4; ++r)
                    t[mt][nt][r] += (float)fm[nt][mt][r];
            float m = -1e30f;
            #pragma unroll
            for (int mt = 0; mt < 4; ++mt)
                #pragma unroll
                for (int r = 0; r < 4; ++r) m = fmaxf(m, t[mt][nt][r]);
            m = fmaxf(m, __shfl_xor(m, 16));
            m = fmaxf(m, __shfl_xor(m, 32));
            float s = 0.f;
            #pragma unroll
            for (int mt = 0; mt < 4; ++mt)
                #pragma unroll
                for (int r = 0; r < 4; ++r) {
                    float p = __expf(t[mt][nt][r] - m);
                    t[mt][nt][r] = p;
                    s += p;
                }
            s += __shfl_xor(s, 16);
            s += __shfl_xor(s, 32);
            float inv = 1.f / s;
            #pragma unroll
            for (int mt = 0; mt < 4; ++mt)
                #pragma unroll
                for (int r = 0; r < 4; ++r) t[mt][nt][r] *= inv;
        }

        // pack P (t dies)
        unsigned pp[4][4][2];   // [mt][nt][half]
        #pragma unroll
        for (int mt = 0; mt < 4; ++mt)
            #pragma unroll
            for (int nt = 0; nt < 4; ++nt) {
                pp[mt][nt][0] = pk2(t[mt][nt][0], t[mt][nt][1]);
                pp[mt][nt][1] = pk2(t[mt][nt][2], t[mt][nt][3]);
            }

        // O^T = V^T @ P^T : contraction over kv-token (2 x 32)
        f32x4 o[2][4];
        #pragma unroll
        for (int dt = 0; dt < 2; ++dt)
            #pragma unroll
            for (int nt = 0; nt < 4; ++nt) { f32x4 z = {0.f,0.f,0.f,0.f}; o[dt][nt] = z; }
        #pragma unroll
        for (int kc = 0; kc < 2; ++kc) {
            half8 va[2], pf[4];
            #pragma unroll
            for (int dt = 0; dt < 2; ++dt) BUILD_FRAG(va[dt], vp[kc*2+0][dt], vp[kc*2+1][dt]);
            #pragma unroll
            for (int nt = 0; nt < 4; ++nt) BUILD_FRAG(pf[nt], pp[kc*2+0][nt], pp[kc*2+1][nt]);
            #pragma unroll
            for (int dt = 0; dt < 2; ++dt)
                #pragma unroll
                for (int nt = 0; nt < 4; ++nt)
                    o[dt][nt] = __builtin_amdgcn_mfma_f32_16x16x32_f16(va[dt], pf[nt], o[dt][nt], 0, 0, 0);
        }

        // hoist Phase D weight loads (global, independent of bar3)
        half8 wbp[8][2];
        #pragma unroll
        for (int kc = 0; kc < 8; ++kc) {
            int k0 = kc * 32 + g * 8;
            #pragma unroll
            for (int ft = 0; ft < 2; ++ft)
                wbp[kc][ft] = *(const half8*)(w16 + 196608 + (jf0 + ft * 16 + l15) * 256 + k0);
        }

        // O[i][jf0+dt*16+g*4+r] -> sB token-major (i = nt*16+l15)
        #pragma unroll
        for (int nt = 0; nt < 4; ++nt) {
            int i = nt * 16 + l15;
            #pragma unroll
            for (int dt = 0; dt < 2; ++dt) {
                half4v ov;
                ov[0] = (half_t)o[dt][nt][0];
                ov[1] = (half_t)o[dt][nt][1];
                ov[2] = (half_t)o[dt][nt][2];
                ov[3] = (half_t)o[dt][nt][3];
                *(half4v*)(sm + S_B + i * ROWB + (jf0 + dt * 16 + g * 4) * 2) = ov;
            }
        }
        __syncthreads();   // bar3: O visible

        // ---------------- Phase D: out = O @ proj_w^T + proj_b ----------------
        f32x4 acc[4][2];
        #pragma unroll
        for (int mt = 0; mt < 4; ++mt)
            #pragma unroll
            for (int ft = 0; ft < 2; ++ft) { f32x4 z = {0.f,0.f,0.f,0.f}; acc[mt][ft] = z; }
        #pragma unroll
        for (int kc = 0; kc < 8; ++kc) {
            int k0 = kc * 32 + g * 8;
            half8 a[4];
            #pragma unroll
            for (int mt = 0; mt < 4; ++mt)
                a[mt] = *(const half8*)(sm + S_B + (mt * 16 + l15) * ROWB + k0 * 2);
            #pragma unroll
            for (int mt = 0; mt < 4; ++mt)
                #pragma unroll
                for (int ft = 0; ft < 2; ++ft)
                    acc[mt][ft] = __builtin_amdgcn_mfma_f32_16x16x32_f16(a[mt], wbp[kc][ft], acc[mt][ft], 0, 0, 0);
        }
        float* ob = out + (size_t)b * 16384;
        #pragma unroll
        for (int ft = 0; ft < 2; ++ft) {
            int jf = jf0 + ft * 16 + l15;
            float pbv = proj_b[jf];
            #pragma unroll
            for (int mt = 0; mt < 4; ++mt)
                #pragma unroll
                for (int r = 0; r < 4; ++r) {
                    int i = mt * 16 + g * 4 + r;
                    ob[i * 256 + jf] = acc[mt][ft][r] + pbv;
                }
        }
    }
}

extern "C" void kernel_launch(void* const* d_in, const int* in_sizes, int n_in,
                              void* d_out, int out_size, void* d_ws, size_t ws_size,
                              hipStream_t stream) {
    const float* x      = (const float*)d_in[0];
    const float* y      = (const float*)d_in[1];
    const float* mask   = (const float*)d_in[2];
    const float* q_w    = (const float*)d_in[3];
    const float* q_b    = (const float*)d_in[4];
    const float* kv_w   = (const float*)d_in[5];
    const float* kv_b   = (const float*)d_in[6];
    const float* proj_w = (const float*)d_in[7];
    const float* proj_b = (const float*)d_in[8];
    const float* rpb    = (const float*)d_in[9];

    half_t* w16   = (half_t*)d_ws;                       // 262144 f16 = 512KB
    half_t* fused = (half_t*)((char*)d_ws + 524288);     // 131072 f16 = 256KB

    swin_prep<<<1536, 256, 0, stream>>>(q_w, kv_w, proj_w, rpb, mask, w16, fused);
    swin_main<<<4096, 512, 0, stream>>>(x, y, q_b, kv_b, proj_b,
                                        w16, fused, (float*)d_out);
}

// Round 5
// 469.428 us; speedup vs baseline: 1.1037x; 1.1037x over previous
//
#include <hip/hip_runtime.h>

typedef _Float16 half_t;
typedef _Float16 half8  __attribute__((ext_vector_type(8)));
typedef _Float16 half4v __attribute__((ext_vector_type(4)));
typedef float    f32x4  __attribute__((ext_vector_type(4)));

#define ROWB   528          // padded row stride (bytes) for 64x256 f16 tiles
#define S_A    0            // x staging (read by Phase B; never overwritten)
#define S_B    33792        // y staging (read by Phase A) -> O (token-major)
#define SMEM_BYTES 67584    // 66 KB -> 2 blocks/CU
#define SCALE  0.17677669529663687f

// ---- prep: weights f32->f16 (q_w pre-scaled); fused bias+mask f16 [4][8][64][64]
__global__ __launch_bounds__(256) void swin_prep(
    const float* __restrict__ q_w, const float* __restrict__ kv_w,
    const float* __restrict__ proj_w, const float* __restrict__ rpb,
    const float* __restrict__ mask,
    half_t* __restrict__ w16, half_t* __restrict__ fused)
{
    int t = blockIdx.x * 256 + threadIdx.x;
    if (t < 65536)        w16[t] = (half_t)(q_w[t] * SCALE);
    else if (t < 196608)  w16[t] = (half_t)kv_w[t - 65536];
    else if (t < 262144)  w16[t] = (half_t)proj_w[t - 196608];
    else if (t < 393216) {
        int u = t - 262144;                 // [0, 131072)
        int cls = u >> 15, rest = u & 32767;
        int h = rest >> 12, i = (rest >> 6) & 63, j = rest & 63;
        int idx = ((i >> 3) - (j >> 3) + 7) * 15 + ((i & 7) - (j & 7) + 7);
        int wsel = (cls == 0) ? 0 : (cls == 1) ? 31 : (cls == 2) ? 992 : 1023;
        fused[u] = (half_t)(rpb[idx * 8 + h] + mask[(size_t)wsel * 4096 + i * 64 + j]);
    }
}

static __device__ __forceinline__ unsigned pk2(float a, float b) {
    union { _Float16 h[2]; unsigned u; } t;
    t.h[0] = (_Float16)a; t.h[1] = (_Float16)b; return t.u;
}

// C-layout (contraction axis on g*4+r over two 16-tiles) -> A/B-frag (contraction
// axis on g*8+e), l15 axis preserved. P0/P1 = the two 16-tile packed pairs.
#define BUILD_FRAG(dst, P0, P1)                                          \
    do {                                                                 \
        union { unsigned u[4]; half8 h; } _u;                            \
        _Pragma("unroll")                                                \
        for (int p = 0; p < 4; ++p) {                                    \
            int _src = (p >> 1) ? srcB : srcA;                           \
            unsigned _rlo = (unsigned)__shfl((int)(P0)[p & 1], _src);    \
            unsigned _rhi = (unsigned)__shfl((int)(P1)[p & 1], _src);    \
            _u.u[p] = hi ? _rhi : _rlo;                                  \
        }                                                                \
        dst = _u.h;                                                      \
    } while (0)

__global__ __launch_bounds__(512, 2) void swin_main(
    const float* __restrict__ x, const float* __restrict__ y,
    const float* __restrict__ q_b, const float* __restrict__ kv_b,
    const float* __restrict__ proj_b,
    const half_t* __restrict__ w16, const half_t* __restrict__ fused,
    float* __restrict__ out)
{
    __shared__ __align__(16) char sm[SMEM_BYTES];
    const int tid  = threadIdx.x;
    const int w    = tid >> 6;       // wave = head
    const int lane = tid & 63;
    const int l15  = lane & 15;
    const int g    = lane >> 4;      // 16-lane group 0..3
    const int b    = blockIdx.x;
    const int jf0  = w * 32;
    const int srcA = ((2 * g) & 3) * 16 + l15;
    const int srcB = ((2 * g + 1) & 3) * 16 + l15;
    const int hi   = g >> 1;

    const float* xb = x + (size_t)b * 16384;
    const float* yb = y + (size_t)b * 16384;
    const half_t* wkv = w16 + 65536;

    // ---------------- P0: stage x,y as f16 (batched burst) ----------------
    {
        float4 fx[8], fy[8];
        #pragma unroll
        for (int it = 0; it < 4; ++it) {
            int c = tid + it * 512;
            int row = c >> 5, c8 = c & 31;
            fx[it*2+0] = *(const float4*)(xb + row * 256 + c8 * 8);
            fx[it*2+1] = *(const float4*)(xb + row * 256 + c8 * 8 + 4);
            fy[it*2+0] = *(const float4*)(yb + row * 256 + c8 * 8);
            fy[it*2+1] = *(const float4*)(yb + row * 256 + c8 * 8 + 4);
        }
        #pragma unroll
        for (int it = 0; it < 4; ++it) {
            int c = tid + it * 512;
            int row = c >> 5, c8 = c & 31;
            half8 hx, hy;
            #pragma unroll
            for (int e = 0; e < 4; ++e) {
                hx[e]   = (half_t)(&fx[it*2+0].x)[e];
                hx[e+4] = (half_t)(&fx[it*2+1].x)[e];
                hy[e]   = (half_t)(&fy[it*2+0].x)[e];
                hy[e+4] = (half_t)(&fy[it*2+1].x)[e];
            }
            int off = row * ROWB + c8 * 16;
            *(half8*)(sm + S_A + off) = hx;
            *(half8*)(sm + S_B + off) = hy;
        }
    }
    __syncthreads();   // bar1: staging visible

    // ---------------- Phase A: K^T, V from y (reads sB; no barrier after) ----------------
    f32x4 kacc[2][4], vacc[4][2];
    #pragma unroll
    for (int ft = 0; ft < 2; ++ft)
        #pragma unroll
        for (int tok = 0; tok < 4; ++tok) {
            f32x4 z = {0.f,0.f,0.f,0.f}; kacc[ft][tok] = z; vacc[tok][ft] = z;
        }
    #pragma unroll
    for (int kh = 0; kh < 4; ++kh) {
        half8 wbk[2][2], wbv[2][2];
        #pragma unroll
        for (int k2 = 0; k2 < 2; ++k2) {
            int k0 = (kh * 2 + k2) * 32 + g * 8;
            #pragma unroll
            for (int ft = 0; ft < 2; ++ft) {
                int jf = jf0 + ft * 16 + l15;
                wbk[k2][ft] = *(const half8*)(wkv + jf * 256 + k0);
                wbv[k2][ft] = *(const half8*)(wkv + (256 + jf) * 256 + k0);
            }
        }
        #pragma unroll
        for (int k2 = 0; k2 < 2; ++k2) {
            int k0 = (kh * 2 + k2) * 32 + g * 8;
            half8 a[4];
            #pragma unroll
            for (int tok = 0; tok < 4; ++tok)
                a[tok] = *(const half8*)(sm + S_B + (tok * 16 + l15) * ROWB + k0 * 2);
            #pragma unroll
            for (int ft = 0; ft < 2; ++ft)
                #pragma unroll
                for (int tok = 0; tok < 4; ++tok) {
                    kacc[ft][tok] = __builtin_amdgcn_mfma_f32_16x16x32_f16(wbk[k2][ft], a[tok], kacc[ft][tok], 0, 0, 0);
                    vacc[tok][ft] = __builtin_amdgcn_mfma_f32_16x16x32_f16(a[tok], wbv[k2][ft], vacc[tok][ft], 0, 0, 0);
                }
        }
    }

    // pack K^T (+bias, feature on g*4+r) and V (+bias, feature on l15); acc die
    unsigned kp[2][4][2], vp[4][2][2];
    #pragma unroll
    for (int ft = 0; ft < 2; ++ft) {
        float4 kb4 = *(const float4*)(kv_b + jf0 + ft * 16 + g * 4);
        #pragma unroll
        for (int tok = 0; tok < 4; ++tok) {
            kp[ft][tok][0] = pk2(kacc[ft][tok][0] + kb4.x, kacc[ft][tok][1] + kb4.y);
            kp[ft][tok][1] = pk2(kacc[ft][tok][2] + kb4.z, kacc[ft][tok][3] + kb4.w);
        }
    }
    #pragma unroll
    for (int ft = 0; ft < 2; ++ft) {
        float vb = kv_b[256 + jf0 + ft * 16 + l15];
        #pragma unroll
        for (int tok = 0; tok < 4; ++tok) {
            vp[tok][ft][0] = pk2(vacc[tok][ft][0] + vb, vacc[tok][ft][1] + vb);
            vp[tok][ft][1] = pk2(vacc[tok][ft][2] + vb, vacc[tok][ft][3] + vb);
        }
    }

    // ---------------- Phase B: Q^T = (w_q*scale) @ x^T (reads sA) ----------------
    unsigned qp[2][4][2];
    {
        f32x4 qacc[2][4];
        #pragma unroll
        for (int ft = 0; ft < 2; ++ft)
            #pragma unroll
            for (int tok = 0; tok < 4; ++tok) { f32x4 z = {0.f,0.f,0.f,0.f}; qacc[ft][tok] = z; }
        #pragma unroll
        for (int kh = 0; kh < 4; ++kh) {
            half8 wbq[2][2];
            #pragma unroll
            for (int k2 = 0; k2 < 2; ++k2) {
                int k0 = (kh * 2 + k2) * 32 + g * 8;
                #pragma unroll
                for (int ft = 0; ft < 2; ++ft)
                    wbq[k2][ft] = *(const half8*)(w16 + (jf0 + ft * 16 + l15) * 256 + k0);
            }
            #pragma unroll
            for (int k2 = 0; k2 < 2; ++k2) {
                int k0 = (kh * 2 + k2) * 32 + g * 8;
                half8 a[4];
                #pragma unroll
                for (int tok = 0; tok < 4; ++tok)
                    a[tok] = *(const half8*)(sm + S_A + (tok * 16 + l15) * ROWB + k0 * 2);
                #pragma unroll
                for (int ft = 0; ft < 2; ++ft)
                    #pragma unroll
                    for (int tok = 0; tok < 4; ++tok)
                        qacc[ft][tok] = __builtin_amdgcn_mfma_f32_16x16x32_f16(wbq[k2][ft], a[tok], qacc[ft][tok], 0, 0, 0);
            }
        }
        #pragma unroll
        for (int ft = 0; ft < 2; ++ft) {
            float4 qb4 = *(const float4*)(q_b + jf0 + ft * 16 + g * 4);
            #pragma unroll
            for (int tok = 0; tok < 4; ++tok) {
                qp[ft][tok][0] = pk2(qacc[ft][tok][0] + qb4.x * SCALE, qacc[ft][tok][1] + qb4.y * SCALE);
                qp[ft][tok][1] = pk2(qacc[ft][tok][2] + qb4.z * SCALE, qacc[ft][tok][3] + qb4.w * SCALE);
            }
        }
    }

    // ---------------- Phase C: attention, all in registers ----------------
    f32x4 o[2][4];
    {
        // build K,Q frags from packed regs (kp/qp die here)
        half8 ka[4], qf[4];
        #pragma unroll
        for (int mt = 0; mt < 4; ++mt) BUILD_FRAG(ka[mt], kp[0][mt], kp[1][mt]);
        #pragma unroll
        for (int nt = 0; nt < 4; ++nt) BUILD_FRAG(qf[nt], qp[0][nt], qp[1][nt]);

        // S^T = K @ Q^T : t[mt][nt][r] -> j = mt*16+g*4+r (kv), i = nt*16+l15 (q)
        f32x4 t[4][4];
        #pragma unroll
        for (int mt = 0; mt < 4; ++mt)
            #pragma unroll
            for (int nt = 0; nt < 4; ++nt) {
                f32x4 z = {0.f,0.f,0.f,0.f};
                t[mt][nt] = __builtin_amdgcn_mfma_f32_16x16x32_f16(ka[mt], qf[nt], z, 0, 0, 0);
            }

        // fused bias+mask (L2-resident), loaded after QK to cap reg pressure
        const int wi = b & 1023;
        const int cls = ((((wi >> 5) == 31) ? 2 : 0)) | (((wi & 31) == 31) ? 1 : 0);
        const half_t* fb = fused + ((size_t)cls * 8 + w) * 4096;
        half4v fm[4][4];   // [nt][mt]
        #pragma unroll
        for (int nt = 0; nt < 4; ++nt)
            #pragma unroll
            for (int mt = 0; mt < 4; ++mt)
                fm[nt][mt] = *(const half4v*)(fb + (nt * 16 + l15) * 64 + mt * 16 + g * 4);

        // softmax over j (within-lane 16 + cross-g shfl)
        #pragma unroll
        for (int nt = 0; nt < 4; ++nt) {
            #pragma unroll
            for (int mt = 0; mt < 4; ++mt)
                #pragma unroll
                for (int r = 0; r < 4; ++r)
                    t[mt][nt][r] += (float)fm[nt][mt][r];
            float m = -1e30f;
            #pragma unroll
            for (int mt = 0; mt < 4; ++mt)
                #pragma unroll
                for (int r = 0; r < 4; ++r) m = fmaxf(m, t[mt][nt][r]);
            m = fmaxf(m, __shfl_xor(m, 16));
            m = fmaxf(m, __shfl_xor(m, 32));
            float s = 0.f;
            #pragma unroll
            for (int mt = 0; mt < 4; ++mt)
                #pragma unroll
                for (int r = 0; r < 4; ++r) {
                    float p = __expf(t[mt][nt][r] - m);
                    t[mt][nt][r] = p;
                    s += p;
                }
            s += __shfl_xor(s, 16);
            s += __shfl_xor(s, 32);
            float inv = 1.f / s;
            #pragma unroll
            for (int mt = 0; mt < 4; ++mt)
                #pragma unroll
                for (int r = 0; r < 4; ++r) t[mt][nt][r] *= inv;
        }

        // pack P (t dies)
        unsigned pp[4][4][2];   // [mt][nt][half]
        #pragma unroll
        for (int mt = 0; mt < 4; ++mt)
            #pragma unroll
            for (int nt = 0; nt < 4; ++nt) {
                pp[mt][nt][0] = pk2(t[mt][nt][0], t[mt][nt][1]);
                pp[mt][nt][1] = pk2(t[mt][nt][2], t[mt][nt][3]);
            }

        // O^T = V^T @ P^T : contraction over kv-token (2 x 32)
        #pragma unroll
        for (int dt = 0; dt < 2; ++dt)
            #pragma unroll
            for (int nt = 0; nt < 4; ++nt) { f32x4 z = {0.f,0.f,0.f,0.f}; o[dt][nt] = z; }
        #pragma unroll
        for (int kc = 0; kc < 2; ++kc) {
            half8 va[2], pf[4];
            #pragma unroll
            for (int dt = 0; dt < 2; ++dt) BUILD_FRAG(va[dt], vp[kc*2+0][dt], vp[kc*2+1][dt]);
            #pragma unroll
            for (int nt = 0; nt < 4; ++nt) BUILD_FRAG(pf[nt], pp[kc*2+0][nt], pp[kc*2+1][nt]);
            #pragma unroll
            for (int dt = 0; dt < 2; ++dt)
                #pragma unroll
                for (int nt = 0; nt < 4; ++nt)
                    o[dt][nt] = __builtin_amdgcn_mfma_f32_16x16x32_f16(va[dt], pf[nt], o[dt][nt], 0, 0, 0);
        }
    }

    __syncthreads();   // bar2: ALL sB (y) reads across waves done -> safe to overwrite

    // O[i][jf0+dt*16+g*4+r] -> sB token-major (i = nt*16+l15)
    #pragma unroll
    for (int nt = 0; nt < 4; ++nt) {
        int i = nt * 16 + l15;
        #pragma unroll
        for (int dt = 0; dt < 2; ++dt) {
            half4v ov;
            ov[0] = (half_t)o[dt][nt][0];
            ov[1] = (half_t)o[dt][nt][1];
            ov[2] = (half_t)o[dt][nt][2];
            ov[3] = (half_t)o[dt][nt][3];
            *(half4v*)(sm + S_B + i * ROWB + (jf0 + dt * 16 + g * 4) * 2) = ov;
        }
    }
    __syncthreads();   // bar3: O visible

    // ---------------- Phase D: out = O @ proj_w^T + proj_b ----------------
    {
        const half_t* wp = w16 + 196608;
        f32x4 dacc[4][2];   // [mt: token tile][ft] ; token on l15, jf on g*4+r
        #pragma unroll
        for (int mt = 0; mt < 4; ++mt)
            #pragma unroll
            for (int ft = 0; ft < 2; ++ft) { f32x4 z = {0.f,0.f,0.f,0.f}; dacc[mt][ft] = z; }
        #pragma unroll
        for (int kh = 0; kh < 4; ++kh) {
            half8 wbp[2][2];
            #pragma unroll
            for (int k2 = 0; k2 < 2; ++k2) {
                int k0 = (kh * 2 + k2) * 32 + g * 8;
                #pragma unroll
                for (int ft = 0; ft < 2; ++ft)
                    wbp[k2][ft] = *(const half8*)(wp + (jf0 + ft * 16 + l15) * 256 + k0);
            }
            #pragma unroll
            for (int k2 = 0; k2 < 2; ++k2) {
                int k0 = (kh * 2 + k2) * 32 + g * 8;
                half8 a[4];
                #pragma unroll
                for (int mt = 0; mt < 4; ++mt)
                    a[mt] = *(const half8*)(sm + S_B + (mt * 16 + l15) * ROWB + k0 * 2);
                #pragma unroll
                for (int mt = 0; mt < 4; ++mt)
                    #pragma unroll
                    for (int ft = 0; ft < 2; ++ft)
                        dacc[mt][ft] = __builtin_amdgcn_mfma_f32_16x16x32_f16(wbp[k2][ft], a[mt], dacc[mt][ft], 0, 0, 0);
            }
        }
        float* ob = out + (size_t)b * 16384;
        #pragma unroll
        for (int ft = 0; ft < 2; ++ft) {
            float4 pb4 = *(const float4*)(proj_b + jf0 + ft * 16 + g * 4);
            #pragma unroll
            for (int mt = 0; mt < 4; ++mt) {
                float4 v;
                v.x = dacc[mt][ft][0] + pb4.x;
                v.y = dacc[mt][ft][1] + pb4.y;
                v.z = dacc[mt][ft][2] + pb4.z;
                v.w = dacc[mt][ft][3] + pb4.w;
                *(float4*)(ob + (mt * 16 + l15) * 256 + jf0 + ft * 16 + g * 4) = v;
            }
        }
    }
}

extern "C" void kernel_launch(void* const* d_in, const int* in_sizes, int n_in,
                              void* d_out, int out_size, void* d_ws, size_t ws_size,
                              hipStream_t stream) {
    const float* x      = (const float*)d_in[0];
    const float* y      = (const float*)d_in[1];
    const float* mask   = (const float*)d_in[2];
    const float* q_w    = (const float*)d_in[3];
    const float* q_b    = (const float*)d_in[4];
    const float* kv_w   = (const float*)d_in[5];
    const float* kv_b   = (const float*)d_in[6];
    const float* proj_w = (const float*)d_in[7];
    const float* proj_b = (const float*)d_in[8];
    const float* rpb    = (const float*)d_in[9];

    half_t* w16   = (half_t*)d_ws;                       // 262144 f16 = 512KB
    half_t* fused = (half_t*)((char*)d_ws + 524288);     // 131072 f16 = 256KB

    swin_prep<<<1536, 256, 0, stream>>>(q_w, kv_w, proj_w, rpb, mask, w16, fused);
    swin_main<<<4096, 512, 0, stream>>>(x, y, q_b, kv_b, proj_b,
                                        w16, fused, (float*)d_out);
}